// Round 8
// baseline (185.961 us; speedup 1.0000x reference)
//
#include <hip/hip_runtime.h>
#include <math.h>

// EnergyCoulomb: B=32, N=512, D=1024, H=512
// R8: R7 + double-buffered LDS for BOTH operands, ONE barrier per K-step.
//     Loads for kt+32 are issued before computing kt, so the compiler's
//     pre-barrier vmcnt(0) drain waits on loads that are ~600 cyc old.
//     (R4 tested A-dbuf + B-direct; B-direct was the regression. This is
//     the untested dbuf-both cell.) Conflict-free LDS geometry unchanged.

typedef unsigned short u16;
typedef unsigned int u32;
typedef __bf16 bf16x8 __attribute__((ext_vector_type(8)));
typedef float f32x4 __attribute__((ext_vector_type(4)));

#define GK 1024

#define GLOAD_LDS16(g, l) __builtin_amdgcn_global_load_lds( \
    (const __attribute__((address_space(1))) void*)(g),     \
    (__attribute__((address_space(3))) void*)(l), 16, 0, 0)

__device__ __forceinline__ u16 f2bf(float f) {
    u32 u = __float_as_uint(f);
    return (u16)((u + 0x7FFFu + ((u >> 16) & 1u)) >> 16);
}

__device__ __forceinline__ float ssp_f(float x) {
    return __logf(0.5f * (__expf(x) + 1.0f));
}

__device__ __forceinline__ float ssp_slow(float x) {
    return fmaxf(x, 0.0f) + log1pf(expf(-fabsf(x))) - 0.6931471805599453f;
}

// ---------------- prep: conv_a + conv_w + out zero (R3-verified) ------

__global__ __launch_bounds__(256) void prep(
    const float* __restrict__ rep, const float* __restrict__ W1,
    const float* __restrict__ Wc1, u16* __restrict__ Abf,
    u16* __restrict__ Btb, float* __restrict__ out)
{
    __shared__ float tile[32][33];
    const int blk = blockIdx.x;
    const int t = threadIdx.x;
    if (blk < 8192) {
        int i = (blk * 256 + t) * 8;
        float4 x = *(const float4*)(rep + i);
        float4 y = *(const float4*)(rep + i + 4);
        union { u16 h[8]; uint4 v; } o;
        o.h[0] = f2bf(x.x); o.h[1] = f2bf(x.y); o.h[2] = f2bf(x.z); o.h[3] = f2bf(x.w);
        o.h[4] = f2bf(y.x); o.h[5] = f2bf(y.y); o.h[6] = f2bf(y.z); o.h[7] = f2bf(y.w);
        *(uint4*)(Abf + i) = o.v;
        if (blk == 0 && t < 32) out[t] = 0.0f;
    } else {
        const int bb = blk - 8192;                  // 0..1023
        const int k0 = (bb & 31) * 32;
        const int n0 = (bb >> 5) * 32;              // 0..1023
        const float* src = (n0 < 512) ? W1 : Wc1;
        const int ns0 = (n0 < 512) ? n0 : n0 - 512;
#pragma unroll
        for (int j = 0; j < 4; j++) {
            int idx = j * 256 + t;
            int kl = idx >> 5, nl = idx & 31;
            tile[kl][nl] = src[(size_t)(k0 + kl) * 512 + ns0 + nl];
        }
        __syncthreads();
#pragma unroll
        for (int j = 0; j < 4; j++) {
            int idx = j * 256 + t;
            int nl = idx >> 5, kl = idx & 31;
            Btb[(size_t)(n0 + nl) * 1024 + k0 + kl] = f2bf(tile[kl][nl]);
        }
    }
}

// ---------------- bf16 MFMA GEMM: BK=32, dbuf, 1 barrier/step ----------------
// LDS chunk geometry per buffer (512 chunks of 16B): physical chunk c:
// line=c>>3, sp=c&7; un=sp^(line&7); row=((un>>2)<<6)|line; k8=un&3.
// Frag read (mrow,q): la=mrow&63, s=(((mrow>>6)<<2)|q)^(la&7), off=(la*8+s)*8.
// [HW-verified R4/R6/R7: SQ_LDS_BANK_CONFLICT = 0]

__global__ __launch_bounds__(256) void gemm_mfma(
    const u16* __restrict__ A,    // [16384][1024] bf16
    const u16* __restrict__ Bt,   // [1024][1024] bf16
    const float* __restrict__ b1, const float* __restrict__ W2,
    const float* __restrict__ bc1, const float* __restrict__ Wc2,
    float* __restrict__ parts)    // [8][16384]
{
    __shared__ u16 As[2][128 * 32];
    __shared__ u16 Bs[2][128 * 32];
    __shared__ float red[2][128];
    const int bm = blockIdx.x;          // 128
    const int bn = blockIdx.y;          // 8
    const int tid = threadIdx.x;
    const int w = tid >> 6, lane = tid & 63;
    const int wave_m = w & 1, wave_n = w >> 1;
    const int lm = lane & 15, q = lane >> 4;

    f32x4 acc[4][4];
#pragma unroll
    for (int i = 0; i < 4; i++)
#pragma unroll
        for (int j = 0; j < 4; j++)
            acc[i][j] = (f32x4){0.0f, 0.0f, 0.0f, 0.0f};

    // staging: 8 GLOADs of 1KB per buffer; 2 per wave; chunk c=(w*2+p)*64+lane
    int goff[2];
#pragma unroll
    for (int p = 0; p < 2; p++) {
        int c = (w * 2 + p) * 64 + lane;
        int line = c >> 3, sp = c & 7;
        int un = sp ^ (line & 7);
        int row = ((un >> 2) << 6) | line;
        int k8 = un & 3;
        goff[p] = row * GK + k8 * 8;    // bf16 elements
    }

    // frag read offsets (u16 elements)
    int aoff[4], boff[4];
#pragma unroll
    for (int i = 0; i < 4; i++) {
        int mrow = wave_m * 64 + i * 16 + lm;
        int la = mrow & 63;
        aoff[i] = la * 64 + ((((mrow >> 6) << 2) | q) ^ (la & 7)) * 8;
        int nrow = wave_n * 64 + i * 16 + lm;
        int lb = nrow & 63;
        boff[i] = lb * 64 + ((((nrow >> 6) << 2) | q) ^ (lb & 7)) * 8;
    }

    const u16* Ab = A + (size_t)(bm * 128) * GK;
    const u16* Bb = Bt + (size_t)(bn * 128) * GK;

    // prologue: stage kt=0 into buf 0
#pragma unroll
    for (int p = 0; p < 2; p++) {
        GLOAD_LDS16(Ab + goff[p], &As[0][(w * 2 + p) << 9]);
        GLOAD_LDS16(Bb + goff[p], &Bs[0][(w * 2 + p) << 9]);
    }
    __syncthreads();                    // buf0 ready (vmcnt drained here)

    for (int kt = 0; kt < GK; kt += 64) {
        // ---- phase 0: stage kt+32 -> buf1, compute kt from buf0 ----
        if (kt + 32 < GK) {
#pragma unroll
            for (int p = 0; p < 2; p++) {
                GLOAD_LDS16(Ab + kt + 32 + goff[p], &As[1][(w * 2 + p) << 9]);
                GLOAD_LDS16(Bb + kt + 32 + goff[p], &Bs[1][(w * 2 + p) << 9]);
            }
        }
        {
            bf16x8 af[4], bfr[4];
#pragma unroll
            for (int i = 0; i < 4; i++) {
                af[i] = *(const bf16x8*)&As[0][aoff[i]];
                bfr[i] = *(const bf16x8*)&Bs[0][boff[i]];
            }
#pragma unroll
            for (int i = 0; i < 4; i++)
#pragma unroll
                for (int j = 0; j < 4; j++)
                    acc[i][j] = __builtin_amdgcn_mfma_f32_16x16x32_bf16(
                        af[i], bfr[j], acc[i][j], 0, 0, 0);
        }
        __syncthreads();                // buf1 ready; buf0 free to overwrite

        // ---- phase 1: stage kt+64 -> buf0, compute kt+32 from buf1 ----
        if (kt + 64 < GK) {
#pragma unroll
            for (int p = 0; p < 2; p++) {
                GLOAD_LDS16(Ab + kt + 64 + goff[p], &As[0][(w * 2 + p) << 9]);
                GLOAD_LDS16(Bb + kt + 64 + goff[p], &Bs[0][(w * 2 + p) << 9]);
            }
        }
        {
            bf16x8 af[4], bfr[4];
#pragma unroll
            for (int i = 0; i < 4; i++) {
                af[i] = *(const bf16x8*)&As[1][aoff[i]];
                bfr[i] = *(const bf16x8*)&Bs[1][boff[i]];
            }
#pragma unroll
            for (int i = 0; i < 4; i++)
#pragma unroll
                for (int j = 0; j < 4; j++)
                    acc[i][j] = __builtin_amdgcn_mfma_f32_16x16x32_bf16(
                        af[i], bfr[j], acc[i][j], 0, 0, 0);
        }
        __syncthreads();                // buf0 ready; buf1 free
    }

    // epilogue (verified since R2)
    const bool is_q = (bn >= 4);
    const float* bb = is_q ? bc1 : b1;
    const float* vv = is_q ? Wc2 : W2;
    const int cb0 = (bn & 3) * 128 + wave_n * 64;
    float bias[4], v[4];
#pragma unroll
    for (int j = 0; j < 4; j++) {
        int c = cb0 + j * 16 + lm;
        bias[j] = bb[c];
        v[j] = vv[c];
    }
#pragma unroll
    for (int i = 0; i < 4; i++) {
#pragma unroll
        for (int r = 0; r < 4; r++) {
            float s = 0.0f;
#pragma unroll
            for (int j = 0; j < 4; j++)
                s += v[j] * ssp_f(acc[i][j][r] + bias[j]);
            s += __shfl_xor(s, 1);
            s += __shfl_xor(s, 2);
            s += __shfl_xor(s, 4);
            s += __shfl_xor(s, 8);
            if (lm == 0) red[wave_n][wave_m * 64 + i * 16 + q * 4 + r] = s;
        }
    }
    __syncthreads();
    if (tid < 128) {
        float val = red[0][tid] + red[1][tid];
        parts[(size_t)((is_q ? 4 : 0) + (bn & 3)) * 16384 + bm * 128 + tid] = val;
    }
}

// ---------------- coulomb: 256 blocks (8 chunks x 32 batches) ----------------

__global__ __launch_bounds__(256) void coulomb_k(
    const float* __restrict__ R, const float* __restrict__ mask,
    const float* __restrict__ parts, const float* __restrict__ b2p,
    const float* __restrict__ bc2p, float* __restrict__ out)
{
    const int N = 512;
    const int b = blockIdx.y;
    const int chunk = blockIdx.x;
    __shared__ float Rx[512], Ry[512], Rz[512], QM[512];
    __shared__ float rbuf[4];
    const int tid = threadIdx.x;
    const float bc2 = bc2p[0];
    const float b2 = b2p[0];

    for (int j = tid; j < N; j += 256) {
        int idx = b * N + j;
        float m = mask[idx];
        const float* rp = R + (size_t)idx * 3;
        Rx[j] = rp[0];
        Ry[j] = rp[1];
        Rz[j] = rp[2];
        float qv = parts[4 * 16384 + idx] + parts[5 * 16384 + idx] +
                   parts[6 * 16384 + idx] + parts[7 * 16384 + idx] + bc2;
        QM[j] = qv * m;
    }
    __syncthreads();

    const int i = chunk * 64 + (tid & 63);
    const int js = (tid >> 6) * 128;
    const float xi = Rx[i], yi = Ry[i], zi = Rz[i], qmi = QM[i];
    float e = 0.0f;
    for (int j = js; j < js + 128; j++) {
        float dx = xi - Rx[j];
        float dy = yi - Ry[j];
        float dz = zi - Rz[j];
        float d2 = dx * dx + dy * dy + dz * dz;
        float t = 1e-5f + sqrtf(d2);
        float term = qmi * QM[j] / (t * t);
        e += (j == i) ? 0.0f : term;
    }
    if (tid < 64) {
        int ii = b * N + chunk * 64 + tid;
        float yv = parts[0 * 16384 + ii] + parts[1 * 16384 + ii] +
                   parts[2 * 16384 + ii] + parts[3 * 16384 + ii] + b2;
        e += yv * mask[ii];
    }
    for (int off = 32; off > 0; off >>= 1) e += __shfl_down(e, off, 64);
    if ((tid & 63) == 0) rbuf[tid >> 6] = e;
    __syncthreads();
    if (tid == 0) atomicAdd(&out[b], rbuf[0] + rbuf[1] + rbuf[2] + rbuf[3]);
}

// ---------------- fp32 fallback (R1) ----------------

#define BM 128
#define BN 64
#define BK 16

__global__ __launch_bounds__(256) void mlp_gemm(
    const float* __restrict__ A, const float* __restrict__ W1,
    const float* __restrict__ Wc1, const float* __restrict__ b1,
    const float* __restrict__ bc1, const float* __restrict__ W2,
    const float* __restrict__ Wc2, float* __restrict__ yi_part,
    float* __restrict__ q_part)
{
    const int K = 1024;
    const int bm = blockIdx.x;
    const int bn = blockIdx.y;
    const bool is_q = (bn >= 8);
    const float* __restrict__ W = is_q ? Wc1 : W1;
    const int j0 = (bn & 7) * BN;

    __shared__ float As[BK][BM + 4];
    __shared__ float Bs[BK][BN + 4];
    __shared__ float red[BM];

    const int tid = threadIdx.x;
    const int tx = tid & 15;
    const int ty = tid >> 4;

    float acc[8][4];
#pragma unroll
    for (int r = 0; r < 8; r++)
#pragma unroll
        for (int c = 0; c < 4; c++) acc[r][c] = 0.0f;

    const int a_row = tid >> 2;
    const int a_k4 = (tid & 3) * 4;
    const float* Arow0 = A + (size_t)(bm * BM + a_row) * K;
    const float* Arow1 = Arow0 + (size_t)64 * K;
    const int w_k = tid >> 4;
    const int w_j = (tid & 15) * 4;

    for (int kt = 0; kt < K; kt += BK) {
        float4 av0 = *(const float4*)(Arow0 + kt + a_k4);
        float4 av1 = *(const float4*)(Arow1 + kt + a_k4);
        float4 wv = *(const float4*)(W + (size_t)(kt + w_k) * 512 + j0 + w_j);
        __syncthreads();
        As[a_k4 + 0][a_row] = av0.x;
        As[a_k4 + 1][a_row] = av0.y;
        As[a_k4 + 2][a_row] = av0.z;
        As[a_k4 + 3][a_row] = av0.w;
        As[a_k4 + 0][a_row + 64] = av1.x;
        As[a_k4 + 1][a_row + 64] = av1.y;
        As[a_k4 + 2][a_row + 64] = av1.z;
        As[a_k4 + 3][a_row + 64] = av1.w;
        *(float4*)&Bs[w_k][w_j] = wv;
        __syncthreads();
#pragma unroll
        for (int kk = 0; kk < BK; kk++) {
            float4 a0 = *(const float4*)&As[kk][ty * 8];
            float4 a1 = *(const float4*)&As[kk][ty * 8 + 4];
            float4 bv = *(const float4*)&Bs[kk][tx * 4];
            float ar[8] = {a0.x, a0.y, a0.z, a0.w, a1.x, a1.y, a1.z, a1.w};
            float bc[4] = {bv.x, bv.y, bv.z, bv.w};
#pragma unroll
            for (int r = 0; r < 8; r++)
#pragma unroll
                for (int c = 0; c < 4; c++)
                    acc[r][c] = fmaf(ar[r], bc[c], acc[r][c]);
        }
    }

    const float* bb = is_q ? bc1 : b1;
    const float* vv = is_q ? Wc2 : W2;
    float bias[4], v[4];
#pragma unroll
    for (int c = 0; c < 4; c++) {
        bias[c] = bb[j0 + tx * 4 + c];
        v[c] = vv[j0 + tx * 4 + c];
    }
    if (tid < BM) red[tid] = 0.0f;
    __syncthreads();
#pragma unroll
    for (int r = 0; r < 8; r++) {
        float s = 0.0f;
#pragma unroll
        for (int c = 0; c < 4; c++)
            s += v[c] * ssp_slow(acc[r][c] + bias[c]);
        atomicAdd(&red[ty * 8 + r], s);
    }
    __syncthreads();
    float* target = is_q ? q_part : yi_part;
    if (tid < BM) atomicAdd(&target[(size_t)bm * BM + tid], red[tid]);
}

__global__ __launch_bounds__(256) void coulomb_fb(
    const float* __restrict__ R, const float* __restrict__ mask,
    const float* __restrict__ yi_part, const float* __restrict__ q_part,
    const float* __restrict__ b2p, const float* __restrict__ bc2p,
    float* __restrict__ out)
{
    const int N = 512;
    const int b = blockIdx.y;
    const int chunk = blockIdx.x;
    __shared__ float Rx[512], Ry[512], Rz[512], QM[512];
    __shared__ float rbuf[4];
    const int tid = threadIdx.x;
    const float bc2 = bc2p[0];
    const float b2 = b2p[0];

    for (int j = tid; j < N; j += 256) {
        float m = mask[b * N + j];
        const float* rp = R + ((size_t)b * N + j) * 3;
        Rx[j] = rp[0];
        Ry[j] = rp[1];
        Rz[j] = rp[2];
        QM[j] = (q_part[b * N + j] + bc2) * m;
    }
    __syncthreads();

    const int i = chunk * 64 + (tid & 63);
    const int js = (tid >> 6) * 128;
    const float xi = Rx[i], yi = Ry[i], zi = Rz[i], qmi = QM[i];
    float e = 0.0f;
    for (int j = js; j < js + 128; j++) {
        float dx = xi - Rx[j];
        float dy = yi - Ry[j];
        float dz = zi - Rz[j];
        float d2 = dx * dx + dy * dy + dz * dz;
        float t = 1e-5f + sqrtf(d2);
        float term = qmi * QM[j] / (t * t);
        e += (j == i) ? 0.0f : term;
    }
    if (tid < 64) {
        int ii = chunk * 64 + tid;
        e += (yi_part[b * N + ii] + b2) * mask[b * N + ii];
    }
    for (int off = 32; off > 0; off >>= 1) e += __shfl_down(e, off, 64);
    if ((tid & 63) == 0) rbuf[tid >> 6] = e;
    __syncthreads();
    if (tid == 0) atomicAdd(&out[b], rbuf[0] + rbuf[1] + rbuf[2] + rbuf[3]);
}

// ---------------- launch ----------------

extern "C" void kernel_launch(void* const* d_in, const int* in_sizes, int n_in,
                              void* d_out, int out_size, void* d_ws, size_t ws_size,
                              hipStream_t stream) {
    const float* rep  = (const float*)d_in[0];
    const float* R    = (const float*)d_in[1];
    const float* mask = (const float*)d_in[2];
    const float* W1   = (const float*)d_in[3];
    const float* b1   = (const float*)d_in[4];
    const float* W2   = (const float*)d_in[5];
    const float* b2   = (const float*)d_in[6];
    const float* Wc1  = (const float*)d_in[7];
    const float* bc1  = (const float*)d_in[8];
    const float* Wc2  = (const float*)d_in[9];
    const float* bc2  = (const float*)d_in[10];
    float* out = (float*)d_out;

    const size_t szA = 16384ull * 1024 * 2;   // 32 MB bf16 A
    const size_t szB = 1024ull * 1024 * 2;    // 2 MB bf16 Bt
    const size_t szP = 8ull * 16384 * 4;      // 512 KB partials
    const size_t need = szA + szB + szP;

    if (ws_size >= need) {
        u16* Abf = (u16*)d_ws;
        u16* Btb = (u16*)((char*)d_ws + szA);
        float* parts = (float*)((char*)d_ws + szA + szB);

        prep<<<8192 + 1024, 256, 0, stream>>>(rep, W1, Wc1, Abf, Btb, out);
        gemm_mfma<<<dim3(128, 8), 256, 0, stream>>>(Abf, Btb, b1, W2, bc1, Wc2, parts);
        coulomb_k<<<dim3(8, 32), 256, 0, stream>>>(R, mask, parts, b2, bc2, out);
    } else {
        float* yi_part = (float*)d_ws;
        float* q_part = yi_part + 16384;
        hipMemsetAsync(d_ws, 0, 2 * 16384 * sizeof(float), stream);
        hipMemsetAsync(d_out, 0, 32 * sizeof(float), stream);
        mlp_gemm<<<dim3(128, 16), 256, 0, stream>>>(rep, W1, Wc1, b1, bc1, W2, Wc2,
                                                    yi_part, q_part);
        coulomb_fb<<<dim3(8, 32), 256, 0, stream>>>(R, mask, yi_part, q_part, b2, bc2, out);
    }
}

// Round 9
// 182.643 us; speedup vs baseline: 1.0182x; 1.0182x over previous
//
#include <hip/hip_runtime.h>
#include <math.h>

// EnergyCoulomb: B=32, N=512, D=1024, H=512
// R9: R7 (best: 182.3us, gemm 58us) + XCD-aware block swizzle in the GEMM.
//     Theory: gemm is L3-bandwidth-bound on A-tile re-reads (8 bn-blocks per
//     bm land on 8 different XCDs under round-robin dispatch -> A pulled from
//     L3 8x = 256MB). Swizzle co-locates all 8 bn-blocks of a bm on ONE XCD
//     (blk%8 = XCD heuristic), consecutive in dispatch order -> A tile hits
//     that XCD's L2 after first fetch. Everything else identical to R7.

typedef unsigned short u16;
typedef unsigned int u32;
typedef __bf16 bf16x8 __attribute__((ext_vector_type(8)));
typedef float f32x4 __attribute__((ext_vector_type(4)));

#define GK 1024

#define GLOAD_LDS16(g, l) __builtin_amdgcn_global_load_lds( \
    (const __attribute__((address_space(1))) void*)(g),     \
    (__attribute__((address_space(3))) void*)(l), 16, 0, 0)

__device__ __forceinline__ u16 f2bf(float f) {
    u32 u = __float_as_uint(f);
    return (u16)((u + 0x7FFFu + ((u >> 16) & 1u)) >> 16);
}

__device__ __forceinline__ float ssp_f(float x) {
    return __logf(0.5f * (__expf(x) + 1.0f));
}

__device__ __forceinline__ float ssp_slow(float x) {
    return fmaxf(x, 0.0f) + log1pf(expf(-fabsf(x))) - 0.6931471805599453f;
}

// ---------------- prep: conv_a + conv_w + out zero (R3-verified) ------

__global__ __launch_bounds__(256) void prep(
    const float* __restrict__ rep, const float* __restrict__ W1,
    const float* __restrict__ Wc1, u16* __restrict__ Abf,
    u16* __restrict__ Btb, float* __restrict__ out)
{
    __shared__ float tile[32][33];
    const int blk = blockIdx.x;
    const int t = threadIdx.x;
    if (blk < 8192) {
        int i = (blk * 256 + t) * 8;
        float4 x = *(const float4*)(rep + i);
        float4 y = *(const float4*)(rep + i + 4);
        union { u16 h[8]; uint4 v; } o;
        o.h[0] = f2bf(x.x); o.h[1] = f2bf(x.y); o.h[2] = f2bf(x.z); o.h[3] = f2bf(x.w);
        o.h[4] = f2bf(y.x); o.h[5] = f2bf(y.y); o.h[6] = f2bf(y.z); o.h[7] = f2bf(y.w);
        *(uint4*)(Abf + i) = o.v;
        if (blk == 0 && t < 32) out[t] = 0.0f;
    } else {
        const int bb = blk - 8192;                  // 0..1023
        const int k0 = (bb & 31) * 32;
        const int n0 = (bb >> 5) * 32;              // 0..1023
        const float* src = (n0 < 512) ? W1 : Wc1;
        const int ns0 = (n0 < 512) ? n0 : n0 - 512;
#pragma unroll
        for (int j = 0; j < 4; j++) {
            int idx = j * 256 + t;
            int kl = idx >> 5, nl = idx & 31;
            tile[kl][nl] = src[(size_t)(k0 + kl) * 512 + ns0 + nl];
        }
        __syncthreads();
#pragma unroll
        for (int j = 0; j < 4; j++) {
            int idx = j * 256 + t;
            int nl = idx >> 5, kl = idx & 31;
            Btb[(size_t)(n0 + nl) * 1024 + k0 + kl] = f2bf(tile[kl][nl]);
        }
    }
}

// ---------------- bf16 MFMA GEMM: BK=32, conflict-free, XCD swizzle ----------
// LDS buffer = 512 chunks of 16B. Physical chunk c: line=c>>3 (128B LDS line),
// sp=c&7; un=sp^(line&7); row=((un>>2)<<6)|line; k8=un&3.
// Frag read (mrow,q): la=mrow&63, s=(((mrow>>6)<<2)|q)^(la&7), off=(la*8+s)*8.
// [HW-verified R4/R6/R7: SQ_LDS_BANK_CONFLICT = 0]

__global__ __launch_bounds__(256) void gemm_mfma(
    const u16* __restrict__ A,    // [16384][1024] bf16
    const u16* __restrict__ Bt,   // [1024][1024] bf16
    const float* __restrict__ b1, const float* __restrict__ W2,
    const float* __restrict__ bc1, const float* __restrict__ Wc2,
    float* __restrict__ parts)    // [8][16384]
{
    __shared__ u16 As[128 * 32];
    __shared__ u16 Bs[128 * 32];
    __shared__ float red[2][128];
    // XCD-aware swizzle (1D grid, 1024 blocks): xcd = blk&7 co-locates the
    // 8 bn-blocks of each bm on one XCD, consecutive in dispatch order.
    const int blk = blockIdx.x;
    const int bm = ((blk & 7) << 4) | (blk >> 6);   // 0..127
    const int bn = (blk >> 3) & 7;                  // 0..7
    const int tid = threadIdx.x;
    const int w = tid >> 6, lane = tid & 63;
    const int wave_m = w & 1, wave_n = w >> 1;
    const int lm = lane & 15, q = lane >> 4;

    f32x4 acc[4][4];
#pragma unroll
    for (int i = 0; i < 4; i++)
#pragma unroll
        for (int j = 0; j < 4; j++)
            acc[i][j] = (f32x4){0.0f, 0.0f, 0.0f, 0.0f};

    // staging: 8 instrs of 1KB per buffer; 2 per wave; chunk c = (w*2+p)*64+lane
    int goff[2];
#pragma unroll
    for (int p = 0; p < 2; p++) {
        int c = (w * 2 + p) * 64 + lane;
        int line = c >> 3, sp = c & 7;
        int un = sp ^ (line & 7);
        int row = ((un >> 2) << 6) | line;
        int k8 = un & 3;
        goff[p] = row * GK + k8 * 8;    // bf16 elements
    }

    // frag read offsets (u16 elements)
    int aoff[4], boff[4];
#pragma unroll
    for (int i = 0; i < 4; i++) {
        int mrow = wave_m * 64 + i * 16 + lm;
        int la = mrow & 63;
        aoff[i] = la * 64 + ((((mrow >> 6) << 2) | q) ^ (la & 7)) * 8;
        int nrow = wave_n * 64 + i * 16 + lm;
        int lb = nrow & 63;
        boff[i] = lb * 64 + ((((nrow >> 6) << 2) | q) ^ (lb & 7)) * 8;
    }

    const u16* Ab = A + (size_t)(bm * 128) * GK;
    const u16* Bb = Bt + (size_t)(bn * 128) * GK;

    for (int kt = 0; kt < GK; kt += 32) {
#pragma unroll
        for (int p = 0; p < 2; p++) {
            GLOAD_LDS16(Ab + kt + goff[p], &As[(w * 2 + p) << 9]);
            GLOAD_LDS16(Bb + kt + goff[p], &Bs[(w * 2 + p) << 9]);
        }
        __syncthreads();
        bf16x8 af[4], bfr[4];
#pragma unroll
        for (int i = 0; i < 4; i++) {
            af[i] = *(const bf16x8*)&As[aoff[i]];
            bfr[i] = *(const bf16x8*)&Bs[boff[i]];
        }
#pragma unroll
        for (int i = 0; i < 4; i++)
#pragma unroll
            for (int j = 0; j < 4; j++)
                acc[i][j] = __builtin_amdgcn_mfma_f32_16x16x32_bf16(
                    af[i], bfr[j], acc[i][j], 0, 0, 0);
        __syncthreads();
    }

    // epilogue (verified since R2)
    const bool is_q = (bn >= 4);
    const float* bb2 = is_q ? bc1 : b1;
    const float* vv = is_q ? Wc2 : W2;
    const int cb0 = (bn & 3) * 128 + wave_n * 64;
    float bias[4], v[4];
#pragma unroll
    for (int j = 0; j < 4; j++) {
        int c = cb0 + j * 16 + lm;
        bias[j] = bb2[c];
        v[j] = vv[c];
    }
#pragma unroll
    for (int i = 0; i < 4; i++) {
#pragma unroll
        for (int r = 0; r < 4; r++) {
            float s = 0.0f;
#pragma unroll
            for (int j = 0; j < 4; j++)
                s += v[j] * ssp_f(acc[i][j][r] + bias[j]);
            s += __shfl_xor(s, 1);
            s += __shfl_xor(s, 2);
            s += __shfl_xor(s, 4);
            s += __shfl_xor(s, 8);
            if (lm == 0) red[wave_n][wave_m * 64 + i * 16 + q * 4 + r] = s;
        }
    }
    __syncthreads();
    if (tid < 128) {
        float val = red[0][tid] + red[1][tid];
        parts[(size_t)((is_q ? 4 : 0) + (bn & 3)) * 16384 + bm * 128 + tid] = val;
    }
}

// ---------------- coulomb: 256 blocks (8 chunks x 32 batches) ----------------

__global__ __launch_bounds__(256) void coulomb_k(
    const float* __restrict__ R, const float* __restrict__ mask,
    const float* __restrict__ parts, const float* __restrict__ b2p,
    const float* __restrict__ bc2p, float* __restrict__ out)
{
    const int N = 512;
    const int b = blockIdx.y;
    const int chunk = blockIdx.x;
    __shared__ float Rx[512], Ry[512], Rz[512], QM[512];
    __shared__ float rbuf[4];
    const int tid = threadIdx.x;
    const float bc2 = bc2p[0];
    const float b2 = b2p[0];

    for (int j = tid; j < N; j += 256) {
        int idx = b * N + j;
        float m = mask[idx];
        const float* rp = R + (size_t)idx * 3;
        Rx[j] = rp[0];
        Ry[j] = rp[1];
        Rz[j] = rp[2];
        float qv = parts[4 * 16384 + idx] + parts[5 * 16384 + idx] +
                   parts[6 * 16384 + idx] + parts[7 * 16384 + idx] + bc2;
        QM[j] = qv * m;
    }
    __syncthreads();

    const int i = chunk * 64 + (tid & 63);
    const int js = (tid >> 6) * 128;
    const float xi = Rx[i], yi = Ry[i], zi = Rz[i], qmi = QM[i];
    float e = 0.0f;
    for (int j = js; j < js + 128; j++) {
        float dx = xi - Rx[j];
        float dy = yi - Ry[j];
        float dz = zi - Rz[j];
        float d2 = dx * dx + dy * dy + dz * dz;
        float t = 1e-5f + sqrtf(d2);
        float term = qmi * QM[j] / (t * t);
        e += (j == i) ? 0.0f : term;
    }
    if (tid < 64) {
        int ii = b * N + chunk * 64 + tid;
        float yv = parts[0 * 16384 + ii] + parts[1 * 16384 + ii] +
                   parts[2 * 16384 + ii] + parts[3 * 16384 + ii] + b2;
        e += yv * mask[ii];
    }
    for (int off = 32; off > 0; off >>= 1) e += __shfl_down(e, off, 64);
    if ((tid & 63) == 0) rbuf[tid >> 6] = e;
    __syncthreads();
    if (tid == 0) atomicAdd(&out[b], rbuf[0] + rbuf[1] + rbuf[2] + rbuf[3]);
}

// ---------------- fp32 fallback (R1) ----------------

#define BM 128
#define BN 64
#define BK 16

__global__ __launch_bounds__(256) void mlp_gemm(
    const float* __restrict__ A, const float* __restrict__ W1,
    const float* __restrict__ Wc1, const float* __restrict__ b1,
    const float* __restrict__ bc1, const float* __restrict__ W2,
    const float* __restrict__ Wc2, float* __restrict__ yi_part,
    float* __restrict__ q_part)
{
    const int K = 1024;
    const int bm = blockIdx.x;
    const int bn = blockIdx.y;
    const bool is_q = (bn >= 8);
    const float* __restrict__ W = is_q ? Wc1 : W1;
    const int j0 = (bn & 7) * BN;

    __shared__ float As[BK][BM + 4];
    __shared__ float Bs[BK][BN + 4];
    __shared__ float red[BM];

    const int tid = threadIdx.x;
    const int tx = tid & 15;
    const int ty = tid >> 4;

    float acc[8][4];
#pragma unroll
    for (int r = 0; r < 8; r++)
#pragma unroll
        for (int c = 0; c < 4; c++) acc[r][c] = 0.0f;

    const int a_row = tid >> 2;
    const int a_k4 = (tid & 3) * 4;
    const float* Arow0 = A + (size_t)(bm * BM + a_row) * K;
    const float* Arow1 = Arow0 + (size_t)64 * K;
    const int w_k = tid >> 4;
    const int w_j = (tid & 15) * 4;

    for (int kt = 0; kt < K; kt += BK) {
        float4 av0 = *(const float4*)(Arow0 + kt + a_k4);
        float4 av1 = *(const float4*)(Arow1 + kt + a_k4);
        float4 wv = *(const float4*)(W + (size_t)(kt + w_k) * 512 + j0 + w_j);
        __syncthreads();
        As[a_k4 + 0][a_row] = av0.x;
        As[a_k4 + 1][a_row] = av0.y;
        As[a_k4 + 2][a_row] = av0.z;
        As[a_k4 + 3][a_row] = av0.w;
        As[a_k4 + 0][a_row + 64] = av1.x;
        As[a_k4 + 1][a_row + 64] = av1.y;
        As[a_k4 + 2][a_row + 64] = av1.z;
        As[a_k4 + 3][a_row + 64] = av1.w;
        *(float4*)&Bs[w_k][w_j] = wv;
        __syncthreads();
#pragma unroll
        for (int kk = 0; kk < BK; kk++) {
            float4 a0 = *(const float4*)&As[kk][ty * 8];
            float4 a1 = *(const float4*)&As[kk][ty * 8 + 4];
            float4 bv = *(const float4*)&Bs[kk][tx * 4];
            float ar[8] = {a0.x, a0.y, a0.z, a0.w, a1.x, a1.y, a1.z, a1.w};
            float bc[4] = {bv.x, bv.y, bv.z, bv.w};
#pragma unroll
            for (int r = 0; r < 8; r++)
#pragma unroll
                for (int c = 0; c < 4; c++)
                    acc[r][c] = fmaf(ar[r], bc[c], acc[r][c]);
        }
    }

    const float* bb = is_q ? bc1 : b1;
    const float* vv = is_q ? Wc2 : W2;
    float bias[4], v[4];
#pragma unroll
    for (int c = 0; c < 4; c++) {
        bias[c] = bb[j0 + tx * 4 + c];
        v[c] = vv[j0 + tx * 4 + c];
    }
    if (tid < BM) red[tid] = 0.0f;
    __syncthreads();
#pragma unroll
    for (int r = 0; r < 8; r++) {
        float s = 0.0f;
#pragma unroll
        for (int c = 0; c < 4; c++)
            s += v[c] * ssp_slow(acc[r][c] + bias[c]);
        atomicAdd(&red[ty * 8 + r], s);
    }
    __syncthreads();
    float* target = is_q ? q_part : yi_part;
    if (tid < BM) atomicAdd(&target[(size_t)bm * BM + tid], red[tid]);
}

__global__ __launch_bounds__(256) void coulomb_fb(
    const float* __restrict__ R, const float* __restrict__ mask,
    const float* __restrict__ yi_part, const float* __restrict__ q_part,
    const float* __restrict__ b2p, const float* __restrict__ bc2p,
    float* __restrict__ out)
{
    const int N = 512;
    const int b = blockIdx.y;
    const int chunk = blockIdx.x;
    __shared__ float Rx[512], Ry[512], Rz[512], QM[512];
    __shared__ float rbuf[4];
    const int tid = threadIdx.x;
    const float bc2 = bc2p[0];
    const float b2 = b2p[0];

    for (int j = tid; j < N; j += 256) {
        float m = mask[b * N + j];
        const float* rp = R + ((size_t)b * N + j) * 3;
        Rx[j] = rp[0];
        Ry[j] = rp[1];
        Rz[j] = rp[2];
        QM[j] = (q_part[b * N + j] + bc2) * m;
    }
    __syncthreads();

    const int i = chunk * 64 + (tid & 63);
    const int js = (tid >> 6) * 128;
    const float xi = Rx[i], yi = Ry[i], zi = Rz[i], qmi = QM[i];
    float e = 0.0f;
    for (int j = js; j < js + 128; j++) {
        float dx = xi - Rx[j];
        float dy = yi - Ry[j];
        float dz = zi - Rz[j];
        float d2 = dx * dx + dy * dy + dz * dz;
        float t = 1e-5f + sqrtf(d2);
        float term = qmi * QM[j] / (t * t);
        e += (j == i) ? 0.0f : term;
    }
    if (tid < 64) {
        int ii = chunk * 64 + tid;
        e += (yi_part[b * N + ii] + b2) * mask[b * N + ii];
    }
    for (int off = 32; off > 0; off >>= 1) e += __shfl_down(e, off, 64);
    if ((tid & 63) == 0) rbuf[tid >> 6] = e;
    __syncthreads();
    if (tid == 0) atomicAdd(&out[b], rbuf[0] + rbuf[1] + rbuf[2] + rbuf[3]);
}

// ---------------- launch ----------------

extern "C" void kernel_launch(void* const* d_in, const int* in_sizes, int n_in,
                              void* d_out, int out_size, void* d_ws, size_t ws_size,
                              hipStream_t stream) {
    const float* rep  = (const float*)d_in[0];
    const float* R    = (const float*)d_in[1];
    const float* mask = (const float*)d_in[2];
    const float* W1   = (const float*)d_in[3];
    const float* b1   = (const float*)d_in[4];
    const float* W2   = (const float*)d_in[5];
    const float* b2   = (const float*)d_in[6];
    const float* Wc1  = (const float*)d_in[7];
    const float* bc1  = (const float*)d_in[8];
    const float* Wc2  = (const float*)d_in[9];
    const float* bc2  = (const float*)d_in[10];
    float* out = (float*)d_out;

    const size_t szA = 16384ull * 1024 * 2;   // 32 MB bf16 A
    const size_t szB = 1024ull * 1024 * 2;    // 2 MB bf16 Bt
    const size_t szP = 8ull * 16384 * 4;      // 512 KB partials
    const size_t need = szA + szB + szP;

    if (ws_size >= need) {
        u16* Abf = (u16*)d_ws;
        u16* Btb = (u16*)((char*)d_ws + szA);
        float* parts = (float*)((char*)d_ws + szA + szB);

        prep<<<8192 + 1024, 256, 0, stream>>>(rep, W1, Wc1, Abf, Btb, out);
        gemm_mfma<<<1024, 256, 0, stream>>>(Abf, Btb, b1, W2, bc1, Wc2, parts);
        coulomb_k<<<dim3(8, 32), 256, 0, stream>>>(R, mask, parts, b2, bc2, out);
    } else {
        float* yi_part = (float*)d_ws;
        float* q_part = yi_part + 16384;
        hipMemsetAsync(d_ws, 0, 2 * 16384 * sizeof(float), stream);
        hipMemsetAsync(d_out, 0, 32 * sizeof(float), stream);
        mlp_gemm<<<dim3(128, 16), 256, 0, stream>>>(rep, W1, Wc1, b1, bc1, W2, Wc2,
                                                    yi_part, q_part);
        coulomb_fb<<<dim3(8, 32), 256, 0, stream>>>(R, mask, yi_part, q_part, b2, bc2, out);
    }
}

// Round 10
// 174.044 us; speedup vs baseline: 1.0685x; 1.0494x over previous
//
#include <hip/hip_runtime.h>
#include <math.h>

// EnergyCoulomb: B=32, N=512, D=1024, H=512
// R10: 256x128 GEMM tile (512 thr, 8 waves 4m x 2n), BK=32, single-buffer
//      2-barrier loop (R7 structure). Theory: gemm is per-CU L2-load-BW
//      bound (time tracks staged bytes across R2..R9); 256-row tile halves
//      B re-staging -> 0.75x bytes/FLOP. Conflict-free LDS geometry extended
//      to 128 lines. prep/coulomb identical to R7/R9.

typedef unsigned short u16;
typedef unsigned int u32;
typedef __bf16 bf16x8 __attribute__((ext_vector_type(8)));
typedef float f32x4 __attribute__((ext_vector_type(4)));

#define GK 1024

#define GLOAD_LDS16(g, l) __builtin_amdgcn_global_load_lds( \
    (const __attribute__((address_space(1))) void*)(g),     \
    (__attribute__((address_space(3))) void*)(l), 16, 0, 0)

__device__ __forceinline__ u16 f2bf(float f) {
    u32 u = __float_as_uint(f);
    return (u16)((u + 0x7FFFu + ((u >> 16) & 1u)) >> 16);
}

__device__ __forceinline__ float ssp_f(float x) {
    return __logf(0.5f * (__expf(x) + 1.0f));
}

__device__ __forceinline__ float ssp_slow(float x) {
    return fmaxf(x, 0.0f) + log1pf(expf(-fabsf(x))) - 0.6931471805599453f;
}

// ---------------- prep: conv_a + conv_w + out zero (R3-verified) ------

__global__ __launch_bounds__(256) void prep(
    const float* __restrict__ rep, const float* __restrict__ W1,
    const float* __restrict__ Wc1, u16* __restrict__ Abf,
    u16* __restrict__ Btb, float* __restrict__ out)
{
    __shared__ float tile[32][33];
    const int blk = blockIdx.x;
    const int t = threadIdx.x;
    if (blk < 8192) {
        int i = (blk * 256 + t) * 8;
        float4 x = *(const float4*)(rep + i);
        float4 y = *(const float4*)(rep + i + 4);
        union { u16 h[8]; uint4 v; } o;
        o.h[0] = f2bf(x.x); o.h[1] = f2bf(x.y); o.h[2] = f2bf(x.z); o.h[3] = f2bf(x.w);
        o.h[4] = f2bf(y.x); o.h[5] = f2bf(y.y); o.h[6] = f2bf(y.z); o.h[7] = f2bf(y.w);
        *(uint4*)(Abf + i) = o.v;
        if (blk == 0 && t < 32) out[t] = 0.0f;
    } else {
        const int bb = blk - 8192;                  // 0..1023
        const int k0 = (bb & 31) * 32;
        const int n0 = (bb >> 5) * 32;              // 0..1023
        const float* src = (n0 < 512) ? W1 : Wc1;
        const int ns0 = (n0 < 512) ? n0 : n0 - 512;
#pragma unroll
        for (int j = 0; j < 4; j++) {
            int idx = j * 256 + t;
            int kl = idx >> 5, nl = idx & 31;
            tile[kl][nl] = src[(size_t)(k0 + kl) * 512 + ns0 + nl];
        }
        __syncthreads();
#pragma unroll
        for (int j = 0; j < 4; j++) {
            int idx = j * 256 + t;
            int nl = idx >> 5, kl = idx & 31;
            Btb[(size_t)(n0 + nl) * 1024 + k0 + kl] = f2bf(tile[kl][nl]);
        }
    }
}

// ---------------- bf16 MFMA GEMM: 256x128 tile, BK=32 ----------------
// As: 1024 chunks of 16B (256 rows x 4 k8), 128 LDS lines of 128B.
//   chunk c: line=c>>3, sp=c&7, un=sp^(line&7); row=line+128*(un>>2); k8=un&3.
//   frag (mrow,q): line=mrow&127, s=(((mrow>>7)<<2)|q)^(line&7),
//   off=(line*8+s)*8.  Same bank structure as the R4/R6/R7-verified geometry
//   (low-3-bit line XOR) -> conflict-free.
// Bs: 512 chunks, exactly R7's verified 64-line geometry.

__global__ __launch_bounds__(512) void gemm_mfma(
    const u16* __restrict__ A,    // [16384][1024] bf16
    const u16* __restrict__ Bt,   // [1024][1024] bf16
    const float* __restrict__ b1, const float* __restrict__ W2,
    const float* __restrict__ bc1, const float* __restrict__ Wc2,
    float* __restrict__ parts)    // [8][16384]
{
    __shared__ u16 As[256 * 32];
    __shared__ u16 Bs[128 * 32];
    __shared__ float red[2][256];
    // swizzle: xcd = blk&7 co-locates blocks sharing bm-high bits
    const int blk = blockIdx.x;                     // 0..511
    const int bm = ((blk & 7) << 3) | (blk >> 6);   // 0..63 (256-row tiles)
    const int bn = (blk >> 3) & 7;                  // 0..7
    const int tid = threadIdx.x;
    const int w = tid >> 6, lane = tid & 63;        // 8 waves
    const int wave_m = w & 3, wave_n = w >> 2;      // 4m x 2n
    const int lm = lane & 15, q = lane >> 4;

    f32x4 acc[4][4];
#pragma unroll
    for (int i = 0; i < 4; i++)
#pragma unroll
        for (int j = 0; j < 4; j++)
            acc[i][j] = (f32x4){0.0f, 0.0f, 0.0f, 0.0f};

    // A staging: 16 instrs of 1KB; 2 per wave; chunk c=(w*2+p)*64+lane
    int gaoff[2];
#pragma unroll
    for (int p = 0; p < 2; p++) {
        int c = (w * 2 + p) * 64 + lane;            // 0..1023
        int line = c >> 3, sp = c & 7;
        int un = sp ^ (line & 7);
        int row = line + 128 * (un >> 2);           // 0..255
        int k8 = un & 3;
        gaoff[p] = row * GK + k8 * 8;               // bf16 elements
    }
    // B staging: 8 instrs of 1KB; 1 per wave; chunk c = w*64+lane (R7 geometry)
    int gboff;
    {
        int c = w * 64 + lane;                      // 0..511
        int line = c >> 3, sp = c & 7;
        int un = sp ^ (line & 7);
        int row = ((un >> 2) << 6) | line;          // 0..127
        int k8 = un & 3;
        gboff = row * GK + k8 * 8;
    }

    // frag read offsets (u16 elements)
    int aoff[4], boff[4];
#pragma unroll
    for (int i = 0; i < 4; i++) {
        int mrow = wave_m * 64 + i * 16 + lm;       // 0..255
        int la = mrow & 127;
        aoff[i] = la * 64 + ((((mrow >> 7) << 2) | q) ^ (la & 7)) * 8;
        int nrow = wave_n * 64 + i * 16 + lm;       // 0..127
        int lb = nrow & 63;
        boff[i] = lb * 64 + ((((nrow >> 6) << 2) | q) ^ (lb & 7)) * 8;
    }

    const u16* Ab = A + (size_t)(bm * 256) * GK;
    const u16* Bb = Bt + (size_t)(bn * 128) * GK;

    for (int kt = 0; kt < GK; kt += 32) {
#pragma unroll
        for (int p = 0; p < 2; p++)
            GLOAD_LDS16(Ab + kt + gaoff[p], &As[(w * 2 + p) << 9]);
        GLOAD_LDS16(Bb + kt + gboff, &Bs[w << 9]);
        __syncthreads();
        bf16x8 af[4], bfr[4];
#pragma unroll
        for (int i = 0; i < 4; i++) {
            af[i] = *(const bf16x8*)&As[aoff[i]];
            bfr[i] = *(const bf16x8*)&Bs[boff[i]];
        }
#pragma unroll
        for (int i = 0; i < 4; i++)
#pragma unroll
            for (int j = 0; j < 4; j++)
                acc[i][j] = __builtin_amdgcn_mfma_f32_16x16x32_bf16(
                    af[i], bfr[j], acc[i][j], 0, 0, 0);
        __syncthreads();
    }

    // epilogue: s = sum_j v[j]*ssp(c+bias[j]); 16-lane shfl reduce;
    // cross-wave (wave_n) combine in LDS; plain store to parts.
    const bool is_q = (bn >= 4);
    const float* bb2 = is_q ? bc1 : b1;
    const float* vv = is_q ? Wc2 : W2;
    const int cb0 = (bn & 3) * 128 + wave_n * 64;
    float bias[4], v[4];
#pragma unroll
    for (int j = 0; j < 4; j++) {
        int c = cb0 + j * 16 + lm;
        bias[j] = bb2[c];
        v[j] = vv[c];
    }
#pragma unroll
    for (int i = 0; i < 4; i++) {
#pragma unroll
        for (int r = 0; r < 4; r++) {
            float s = 0.0f;
#pragma unroll
            for (int j = 0; j < 4; j++)
                s += v[j] * ssp_f(acc[i][j][r] + bias[j]);
            s += __shfl_xor(s, 1);
            s += __shfl_xor(s, 2);
            s += __shfl_xor(s, 4);
            s += __shfl_xor(s, 8);
            if (lm == 0) red[wave_n][wave_m * 64 + i * 16 + q * 4 + r] = s;
        }
    }
    __syncthreads();
    if (tid < 256) {
        float val = red[0][tid] + red[1][tid];
        parts[(size_t)((is_q ? 4 : 0) + (bn & 3)) * 16384 + bm * 256 + tid] = val;
    }
}

// ---------------- coulomb: 256 blocks (8 chunks x 32 batches) ----------------

__global__ __launch_bounds__(256) void coulomb_k(
    const float* __restrict__ R, const float* __restrict__ mask,
    const float* __restrict__ parts, const float* __restrict__ b2p,
    const float* __restrict__ bc2p, float* __restrict__ out)
{
    const int N = 512;
    const int b = blockIdx.y;
    const int chunk = blockIdx.x;
    __shared__ float Rx[512], Ry[512], Rz[512], QM[512];
    __shared__ float rbuf[4];
    const int tid = threadIdx.x;
    const float bc2 = bc2p[0];
    const float b2 = b2p[0];

    for (int j = tid; j < N; j += 256) {
        int idx = b * N + j;
        float m = mask[idx];
        const float* rp = R + (size_t)idx * 3;
        Rx[j] = rp[0];
        Ry[j] = rp[1];
        Rz[j] = rp[2];
        float qv = parts[4 * 16384 + idx] + parts[5 * 16384 + idx] +
                   parts[6 * 16384 + idx] + parts[7 * 16384 + idx] + bc2;
        QM[j] = qv * m;
    }
    __syncthreads();

    const int i = chunk * 64 + (tid & 63);
    const int js = (tid >> 6) * 128;
    const float xi = Rx[i], yi = Ry[i], zi = Rz[i], qmi = QM[i];
    float e = 0.0f;
    for (int j = js; j < js + 128; j++) {
        float dx = xi - Rx[j];
        float dy = yi - Ry[j];
        float dz = zi - Rz[j];
        float d2 = dx * dx + dy * dy + dz * dz;
        float t = 1e-5f + sqrtf(d2);
        float term = qmi * QM[j] / (t * t);
        e += (j == i) ? 0.0f : term;
    }
    if (tid < 64) {
        int ii = b * N + chunk * 64 + tid;
        float yv = parts[0 * 16384 + ii] + parts[1 * 16384 + ii] +
                   parts[2 * 16384 + ii] + parts[3 * 16384 + ii] + b2;
        e += yv * mask[ii];
    }
    for (int off = 32; off > 0; off >>= 1) e += __shfl_down(e, off, 64);
    if ((tid & 63) == 0) rbuf[tid >> 6] = e;
    __syncthreads();
    if (tid == 0) atomicAdd(&out[b], rbuf[0] + rbuf[1] + rbuf[2] + rbuf[3]);
}

// ---------------- fp32 fallback (R1) ----------------

#define BM 128
#define BN 64
#define BK 16

__global__ __launch_bounds__(256) void mlp_gemm(
    const float* __restrict__ A, const float* __restrict__ W1,
    const float* __restrict__ Wc1, const float* __restrict__ b1,
    const float* __restrict__ bc1, const float* __restrict__ W2,
    const float* __restrict__ Wc2, float* __restrict__ yi_part,
    float* __restrict__ q_part)
{
    const int K = 1024;
    const int bm = blockIdx.x;
    const int bn = blockIdx.y;
    const bool is_q = (bn >= 8);
    const float* __restrict__ W = is_q ? Wc1 : W1;
    const int j0 = (bn & 7) * BN;

    __shared__ float As[BK][BM + 4];
    __shared__ float Bs[BK][BN + 4];
    __shared__ float red[BM];

    const int tid = threadIdx.x;
    const int tx = tid & 15;
    const int ty = tid >> 4;

    float acc[8][4];
#pragma unroll
    for (int r = 0; r < 8; r++)
#pragma unroll
        for (int c = 0; c < 4; c++) acc[r][c] = 0.0f;

    const int a_row = tid >> 2;
    const int a_k4 = (tid & 3) * 4;
    const float* Arow0 = A + (size_t)(bm * BM + a_row) * K;
    const float* Arow1 = Arow0 + (size_t)64 * K;
    const int w_k = tid >> 4;
    const int w_j = (tid & 15) * 4;

    for (int kt = 0; kt < K; kt += BK) {
        float4 av0 = *(const float4*)(Arow0 + kt + a_k4);
        float4 av1 = *(const float4*)(Arow1 + kt + a_k4);
        float4 wv = *(const float4*)(W + (size_t)(kt + w_k) * 512 + j0 + w_j);
        __syncthreads();
        As[a_k4 + 0][a_row] = av0.x;
        As[a_k4 + 1][a_row] = av0.y;
        As[a_k4 + 2][a_row] = av0.z;
        As[a_k4 + 3][a_row] = av0.w;
        As[a_k4 + 0][a_row + 64] = av1.x;
        As[a_k4 + 1][a_row + 64] = av1.y;
        As[a_k4 + 2][a_row + 64] = av1.z;
        As[a_k4 + 3][a_row + 64] = av1.w;
        *(float4*)&Bs[w_k][w_j] = wv;
        __syncthreads();
#pragma unroll
        for (int kk = 0; kk < BK; kk++) {
            float4 a0 = *(const float4*)&As[kk][ty * 8];
            float4 a1 = *(const float4*)&As[kk][ty * 8 + 4];
            float4 bv = *(const float4*)&Bs[kk][tx * 4];
            float ar[8] = {a0.x, a0.y, a0.z, a0.w, a1.x, a1.y, a1.z, a1.w};
            float bc[4] = {bv.x, bv.y, bv.z, bv.w};
#pragma unroll
            for (int r = 0; r < 8; r++)
#pragma unroll
                for (int c = 0; c < 4; c++)
                    acc[r][c] = fmaf(ar[r], bc[c], acc[r][c]);
        }
    }

    const float* bb = is_q ? bc1 : b1;
    const float* vv = is_q ? Wc2 : W2;
    float bias[4], v[4];
#pragma unroll
    for (int c = 0; c < 4; c++) {
        bias[c] = bb[j0 + tx * 4 + c];
        v[c] = vv[j0 + tx * 4 + c];
    }
    if (tid < BM) red[tid] = 0.0f;
    __syncthreads();
#pragma unroll
    for (int r = 0; r < 8; r++) {
        float s = 0.0f;
#pragma unroll
        for (int c = 0; c < 4; c++)
            s += v[c] * ssp_slow(acc[r][c] + bias[c]);
        atomicAdd(&red[ty * 8 + r], s);
    }
    __syncthreads();
    float* target = is_q ? q_part : yi_part;
    if (tid < BM) atomicAdd(&target[(size_t)bm * BM + tid], red[tid]);
}

__global__ __launch_bounds__(256) void coulomb_fb(
    const float* __restrict__ R, const float* __restrict__ mask,
    const float* __restrict__ yi_part, const float* __restrict__ q_part,
    const float* __restrict__ b2p, const float* __restrict__ bc2p,
    float* __restrict__ out)
{
    const int N = 512;
    const int b = blockIdx.y;
    const int chunk = blockIdx.x;
    __shared__ float Rx[512], Ry[512], Rz[512], QM[512];
    __shared__ float rbuf[4];
    const int tid = threadIdx.x;
    const float bc2 = bc2p[0];
    const float b2 = b2p[0];

    for (int j = tid; j < N; j += 256) {
        float m = mask[b * N + j];
        const float* rp = R + ((size_t)b * N + j) * 3;
        Rx[j] = rp[0];
        Ry[j] = rp[1];
        Rz[j] = rp[2];
        QM[j] = (q_part[b * N + j] + bc2) * m;
    }
    __syncthreads();

    const int i = chunk * 64 + (tid & 63);
    const int js = (tid >> 6) * 128;
    const float xi = Rx[i], yi = Ry[i], zi = Rz[i], qmi = QM[i];
    float e = 0.0f;
    for (int j = js; j < js + 128; j++) {
        float dx = xi - Rx[j];
        float dy = yi - Ry[j];
        float dz = zi - Rz[j];
        float d2 = dx * dx + dy * dy + dz * dz;
        float t = 1e-5f + sqrtf(d2);
        float term = qmi * QM[j] / (t * t);
        e += (j == i) ? 0.0f : term;
    }
    if (tid < 64) {
        int ii = chunk * 64 + tid;
        e += (yi_part[b * N + ii] + b2) * mask[b * N + ii];
    }
    for (int off = 32; off > 0; off >>= 1) e += __shfl_down(e, off, 64);
    if ((tid & 63) == 0) rbuf[tid >> 6] = e;
    __syncthreads();
    if (tid == 0) atomicAdd(&out[b], rbuf[0] + rbuf[1] + rbuf[2] + rbuf[3]);
}

// ---------------- launch ----------------

extern "C" void kernel_launch(void* const* d_in, const int* in_sizes, int n_in,
                              void* d_out, int out_size, void* d_ws, size_t ws_size,
                              hipStream_t stream) {
    const float* rep  = (const float*)d_in[0];
    const float* R    = (const float*)d_in[1];
    const float* mask = (const float*)d_in[2];
    const float* W1   = (const float*)d_in[3];
    const float* b1   = (const float*)d_in[4];
    const float* W2   = (const float*)d_in[5];
    const float* b2   = (const float*)d_in[6];
    const float* Wc1  = (const float*)d_in[7];
    const float* bc1  = (const float*)d_in[8];
    const float* Wc2  = (const float*)d_in[9];
    const float* bc2  = (const float*)d_in[10];
    float* out = (float*)d_out;

    const size_t szA = 16384ull * 1024 * 2;   // 32 MB bf16 A
    const size_t szB = 1024ull * 1024 * 2;    // 2 MB bf16 Bt
    const size_t szP = 8ull * 16384 * 4;      // 512 KB partials
    const size_t need = szA + szB + szP;

    if (ws_size >= need) {
        u16* Abf = (u16*)d_ws;
        u16* Btb = (u16*)((char*)d_ws + szA);
        float* parts = (float*)((char*)d_ws + szA + szB);

        prep<<<8192 + 1024, 256, 0, stream>>>(rep, W1, Wc1, Abf, Btb, out);
        gemm_mfma<<<512, 512, 0, stream>>>(Abf, Btb, b1, W2, bc1, Wc2, parts);
        coulomb_k<<<dim3(8, 32), 256, 0, stream>>>(R, mask, parts, b2, bc2, out);
    } else {
        float* yi_part = (float*)d_ws;
        float* q_part = yi_part + 16384;
        hipMemsetAsync(d_ws, 0, 2 * 16384 * sizeof(float), stream);
        hipMemsetAsync(d_out, 0, 32 * sizeof(float), stream);
        mlp_gemm<<<dim3(128, 16), 256, 0, stream>>>(rep, W1, Wc1, b1, bc1, W2, Wc2,
                                                    yi_part, q_part);
        coulomb_fb<<<dim3(8, 32), 256, 0, stream>>>(R, mask, yi_part, q_part, b2, bc2, out);
    }
}